// Round 1
// baseline (1294.097 us; speedup 1.0000x reference)
//
#include <hip/hip_runtime.h>
#include <hip/hip_bf16.h>
#include <cstdint>
#include <cstddef>

// Problem dims (fixed by reference)
#define NTOK 4096
#define EDIM 4096
#define IDIM 16384

using i32x4 = __attribute__((ext_vector_type(4))) int;

// ---- async global->LDS, 16B per lane (guide §5: width=16 is the fast path) ----
__device__ __forceinline__ void gload_lds16(const void* g, void* l) {
    __builtin_amdgcn_global_load_lds(
        (const __attribute__((address_space(1))) void*)g,
        (__attribute__((address_space(3))) void*)l,
        16, 0, 0);
}

// ---- int32 -> int8 pack (16 elements per thread, fully vectorized) ----
__global__ __launch_bounds__(256) void pack_i8_kernel(const int* __restrict__ in,
                                                      char* __restrict__ out, int n16) {
    int i = blockIdx.x * blockDim.x + threadIdx.x;
    if (i >= n16) return;
    const i32x4* p = (const i32x4*)in + (size_t)i * 4;
    i32x4 w0 = p[0], w1 = p[1], w2 = p[2], w3 = p[3];
    i32x4 o;
    o.x = (w0.x & 0xff) | ((w0.y & 0xff) << 8) | ((w0.z & 0xff) << 16) | (w0.w << 24);
    o.y = (w1.x & 0xff) | ((w1.y & 0xff) << 8) | ((w1.z & 0xff) << 16) | (w1.w << 24);
    o.z = (w2.x & 0xff) | ((w2.y & 0xff) << 8) | ((w2.z & 0xff) << 16) | (w2.w << 24);
    o.w = (w3.x & 0xff) | ((w3.y & 0xff) << 8) | ((w3.z & 0xff) << 16) | (w3.w << 24);
    *(i32x4*)(out + (size_t)i * 16) = o;
}

// ---- int8 GEMM, m97 structure: 128x128 tile, 4 waves (2x2), BK=64 ----
// A: [M,K] row-major int8.  B: [NC,K] row-major int8 (i.e. B^T input layout).
// GELU=true : out = int8 requant(gelu(acc*s0 + bias_i8[col]*s1))   (fc1)
// GELU=false: out = float(acc)*s0 + bias_f32[col]                  (fc2)
template <int K, bool GELU>
__global__ __launch_bounds__(256) void gemm_i8_kernel(
    const char* __restrict__ A, const char* __restrict__ B, void* __restrict__ outp,
    const int* __restrict__ bias_i8, const float* __restrict__ bias_f32,
    const float* __restrict__ sc0, const float* __restrict__ sc1, int NC) {
    __shared__ char ldsA[128 * 64];
    __shared__ char ldsB[128 * 64];

    const int tid  = threadIdx.x;
    const int lane = tid & 63;
    const int wid  = tid >> 6;
    const int wr   = wid >> 1;           // wave row 0..1  (64-row sub-tile)
    const int wc   = wid & 1;            // wave col 0..1  (64-col sub-tile)
    const int lr   = lane & 15;          // frag row (A) / frag col (B)
    const int lk   = (lane >> 4) * 16;   // frag k-offset (bytes)

    const int brow = blockIdx.y;
    const int bcol = blockIdx.x;

    // Staging: thread t loads 16B at row (t>>2), k-chunk (t&3)*16.
    // LDS dest = tid*16 => linear row-major [row][64B] and wave-uniform-base+lane*16. (m97)
    const char* Ag = A + (size_t)(brow * 128 + (tid >> 2)) * K + (tid & 3) * 16;
    const char* Bg = B + (size_t)(bcol * 128 + (tid >> 2)) * K + (tid & 3) * 16;
    char* la = ldsA + tid * 16;
    char* lb = ldsB + tid * 16;

    i32x4 acc[4][4] = {};

    for (int k0 = 0; k0 < K; k0 += 64) {
        __syncthreads();                               // prior compute done reading LDS
        gload_lds16(Ag + k0, la);                      // rows 0..63
        gload_lds16(Ag + k0 + (size_t)64 * K, la + 4096); // rows 64..127
        gload_lds16(Bg + k0, lb);
        gload_lds16(Bg + k0 + (size_t)64 * K, lb + 4096);
        asm volatile("s_waitcnt vmcnt(0)" ::: "memory");
        __syncthreads();                               // LDS tile visible to all waves

        i32x4 a[4], b[4];
#pragma unroll
        for (int m = 0; m < 4; ++m)
            a[m] = *(const i32x4*)&ldsA[(wr * 64 + m * 16 + lr) * 64 + lk];
#pragma unroll
        for (int n = 0; n < 4; ++n)
            b[n] = *(const i32x4*)&ldsB[(wc * 64 + n * 16 + lr) * 64 + lk];
#pragma unroll
        for (int m = 0; m < 4; ++m)
#pragma unroll
            for (int n = 0; n < 4; ++n)
                acc[m][n] = __builtin_amdgcn_mfma_i32_16x16x64_i8(a[m], b[n], acc[m][n], 0, 0, 0);
    }

    // Epilogue. C/D frag layout (gfx950, dtype-independent): col=lane&15, row=(lane>>4)*4+r.
    const float s0 = sc0[0];
    float s1 = 0.f;
    if (GELU) s1 = sc1[0];
    const int r0 = brow * 128 + wr * 64 + (lane >> 4) * 4;
    const int c0 = bcol * 128 + wc * 64 + (lane & 15);
#pragma unroll
    for (int m = 0; m < 4; ++m) {
#pragma unroll
        for (int n = 0; n < 4; ++n) {
#pragma unroll
            for (int r = 0; r < 4; ++r) {
                const int row = r0 + m * 16 + r;
                const int col = c0 + n * 16;
                float v = (float)acc[m][n][r] * s0;
                if (GELU) {
                    v += (float)bias_i8[col] * s1;
                    // exact GELU: x*0.5*(1+erf(x/sqrt(2))); round-half-even == jnp.round
                    float y = 0.5f * v * (1.f + erff(v * 0.70710678118654752f));
                    float q = fminf(fmaxf(rintf(y), -128.f), 127.f);
                    ((char*)outp)[(size_t)row * NC + col] = (char)(int)q;
                } else {
                    v += bias_f32[col];
                    ((float*)outp)[(size_t)row * NC + col] = v;
                }
            }
        }
    }
}

extern "C" void kernel_launch(void* const* d_in, const int* in_sizes, int n_in,
                              void* d_out, int out_size, void* d_ws, size_t ws_size,
                              hipStream_t stream) {
    // setup_inputs order: x, W1, b1, a1, b1_scale, W2, b2, a2
    const int*   x    = (const int*)d_in[0];    // [N,E] int8-valued int32
    const int*   W1   = (const int*)d_in[1];    // [I,E]
    const int*   b1   = (const int*)d_in[2];    // [I]
    const float* a1   = (const float*)d_in[3];
    const float* b1s  = (const float*)d_in[4];
    const int*   W2   = (const int*)d_in[5];    // [E,I]
    const float* b2   = (const float*)d_in[6];  // [E] fp32
    const float* a2   = (const float*)d_in[7];
    float* out = (float*)d_out;

    // Workspace layout (all int8): x8 | W18 | W28 | h
    const size_t sz_x  = (size_t)NTOK * EDIM;   // 16 MiB
    const size_t sz_w1 = (size_t)IDIM * EDIM;   // 64 MiB
    const size_t sz_w2 = (size_t)EDIM * IDIM;   // 64 MiB
    const size_t sz_h  = (size_t)NTOK * IDIM;   // 64 MiB
    char* x8  = (char*)d_ws;
    char* W18 = x8 + sz_x;
    char* W28 = W18 + sz_w1;
    char* h   = W28 + sz_w2;
    if (ws_size < sz_x + sz_w1 + sz_w2 + sz_h) return;  // fail loudly (wrong output)

    // Pack int32 -> int8 (all counts divisible by 16*256)
    pack_i8_kernel<<<(int)(sz_x  / 16 / 256), 256, 0, stream>>>(x,  x8,  (int)(sz_x  / 16));
    pack_i8_kernel<<<(int)(sz_w1 / 16 / 256), 256, 0, stream>>>(W1, W18, (int)(sz_w1 / 16));
    pack_i8_kernel<<<(int)(sz_w2 / 16 / 256), 256, 0, stream>>>(W2, W28, (int)(sz_w2 / 16));

    // fc1: [N,E] x [I,E]^T -> h int8 [N,I]
    gemm_i8_kernel<EDIM, true><<<dim3(IDIM / 128, NTOK / 128), 256, 0, stream>>>(
        x8, W18, h, b1, nullptr, a1, b1s, IDIM);
    // fc2: [N,I] x [E,I]^T -> out fp32 [N,E]
    gemm_i8_kernel<IDIM, false><<<dim3(EDIM / 128, NTOK / 128), 256, 0, stream>>>(
        h, W28, out, nullptr, b2, a2, nullptr, EDIM);
}